// Round 12
// baseline (234.214 us; speedup 1.0000x reference)
//
#include <hip/hip_runtime.h>
#include <hip/hip_bf16.h>
#include <stdint.h>

// Problem constants
#define DM    2048
#define NH    16
#define NKVH  4
#define HD    128
#define WIN   512
#define SEQL  2048
#define BAT   2
#define MR    (BAT*SEQL)        // 4096 rows
#define NQKV  3072              // 2048 q + 512 k + 512 v
#define QKSCALE 0.08838834764831845f
#define CAP   50.0f
#define C1F (QKSCALE * 2.0f * 1.4426950408889634f / CAP)
#define C2F (-144.26950408889634f)   // -2*CAP*log2e ; p' = 2^(C2F/(2^sv+1))

typedef unsigned short u16;
typedef __attribute__((ext_vector_type(8))) short short8;
typedef __attribute__((ext_vector_type(4))) float f32x4;
typedef __attribute__((ext_vector_type(16))) float f32x16;

__device__ __forceinline__ u16 f2bf(float f) {
  union { float f; uint32_t u; } v; v.f = f;
  uint32_t r = v.u + 0x7FFFu + ((v.u >> 16) & 1u);
  return (u16)(r >> 16);
}
__device__ __forceinline__ float bf2f(u16 h) {
  union { uint32_t u; float f; } v; v.u = ((uint32_t)h) << 16; return v.f;
}
__device__ __forceinline__ void gld16(const void* g, void* l) {
  __builtin_amdgcn_global_load_lds((const __attribute__((address_space(1))) void*)g,
                                   (__attribute__((address_space(3))) void*)l,
                                   16, 0, 0);
}
__device__ __forceinline__ float exp_softcap(float sv) {
  float t = __builtin_amdgcn_exp2f(sv);
  float u = __builtin_amdgcn_rcpf(t + 1.0f);
  return __builtin_amdgcn_exp2f(u * C2F);
}

// ---------------- fused prep: all fp32->bf16 casts + RoPE table, one launch ----------
__global__ void k_prep(const float* __restrict__ hs, const float* __restrict__ wq,
                       const float* __restrict__ wk, const float* __restrict__ wv,
                       const float* __restrict__ wo,
                       u16* __restrict__ A_bf, u16* __restrict__ Wqkv,
                       u16* __restrict__ Wo,
                       float* __restrict__ cosT, float* __restrict__ sinT) {
  const int bid = blockIdx.x;
  if (bid < 18432) {
    const int g = bid * 256 + threadIdx.x;     // float4 index
    const float* src; u16* dst; int off;
    if (g < 2097152)      { src = hs; dst = A_bf;           off = 0; }
    else if (g < 3145728) { src = wq; dst = Wqkv;           off = 2097152; }
    else if (g < 3407872) { src = wk; dst = Wqkv + 4194304; off = 3145728; }
    else if (g < 3670016) { src = wv; dst = Wqkv + 5242880; off = 3407872; }
    else                  { src = wo; dst = Wo;             off = 3670016; }
    const int li = g - off;
    float4 v = ((const float4*)src)[li];
    ushort4 o;
    o.x = f2bf(v.x); o.y = f2bf(v.y); o.z = f2bf(v.z); o.w = f2bf(v.w);
    ((ushort4*)dst)[li] = o;
  } else {
    const int rt = (bid - 18432) * 256 + threadIdx.x;  // 0..131071
    const int s = rt >> 6, i = rt & 63;
    float invf = expf(-(float)i * (9.210340371976184f / 64.0f));
    float a = (float)s * invf;
    cosT[rt] = cosf(a);
    sinT[rt] = sinf(a);
  }
}

// ---------------- fused QKV GEMM: 4-sub-phase in-place-refill counted-vmcnt ----------
// T3/T4 mechanism adapted to 128x128/4M-x-1N: wave wid reads only A-slab wid (sub0)
// and B-slab n2 at sub-phase n2 -> each 32-row slab of the CURRENT buffer dies at a
// known barrier, so tile t+2 refills it in place: A+B0 @sub1, B1 @sub2, B2 @sub3,
// B3 @ next tile's sub0. The tile-top wait is then a uniform vmcnt(8) (8 newer loads
// always in flight) - no drain in the main loop. ds_read->MFMA fenced per rule #18.
// In-register RoPE epilogue unchanged. LDS 64KB -> 2 blocks/CU.
__global__ __launch_bounds__(256, 2) void k_gemm_qkv(const u16* __restrict__ A,
                                                     const u16* __restrict__ Bm,
                                                     u16* __restrict__ qrout,
                                                     u16* __restrict__ krout,
                                                     u16* __restrict__ vtout,
                                                     const float* __restrict__ cosT,
                                                     const float* __restrict__ sinT) {
  __shared__ __align__(16) u16 ldsA[2][128 * 64];   // 32 KB
  __shared__ __align__(16) u16 ldsB[2][128 * 64];   // 32 KB
  const int t = threadIdx.x;
  const int K = DM;

  const int nwg  = gridDim.x * gridDim.y;               // 768, %8==0
  const int flat = blockIdx.y * gridDim.x + blockIdx.x;
  const int cpx  = nwg >> 3;
  const int swz  = (flat & 7) * cpx + (flat >> 3);
  const int bn = swz % gridDim.x, bm = swz / gridDim.x;

  const int m0 = bm * 128, n0 = bn * 128;
  const int lane = t & 63, wid = t >> 6;
  const int lr = lane & 15, lk = lane >> 4;
  const int wr = wid * 32;                              // 4M x 1N
  const int nt = K >> 6;                                // 32

  const int srow = t >> 3;
  const int scol = (((t & 7) ^ (srow & 7)) << 3);       // T2 source swizzle
  const u16* aBase = A  + (size_t)(m0 + srow) * K + scol;
  const u16* bBase = Bm + (size_t)(n0 + srow) * K + scol;

  // slab-stage: one instruction covers 32 rows x 64 K (8 KB) via all 256 threads
  #define STA(p, x, i) gld16(aBase + (size_t)((i) * 32) * K + (x) * 64, &ldsA[p][(i) * 2048 + t * 8])
  #define STB(p, x, i) gld16(bBase + (size_t)((i) * 32) * K + (x) * 64, &ldsB[p][(i) * 2048 + t * 8])

  f32x4 acc[2][8];
  #pragma unroll
  for (int mi = 0; mi < 2; ++mi)
    #pragma unroll
    for (int ni = 0; ni < 8; ++ni) acc[mi][ni] = f32x4{0.f, 0.f, 0.f, 0.f};

  // prologue: tile 0 fully + tile 1 minus B3  (15 instructions)
  STA(0, 0, 0); STA(0, 0, 1); STA(0, 0, 2); STA(0, 0, 3);
  STB(0, 0, 0); STB(0, 0, 1); STB(0, 0, 2); STB(0, 0, 3);
  STA(1, 1, 0); STA(1, 1, 1); STA(1, 1, 2); STA(1, 1, 3);
  STB(1, 1, 0); STB(1, 1, 1); STB(1, 1, 2);

  for (int kt = 0; kt < nt; ++kt) {
    const int cur = kt & 1;
    const u16* la = ldsA[cur];
    const u16* lb = ldsB[cur];

    // ---------- sub0: af (slab wid) + B-slab 0 ----------
    if (kt + 1 < nt) {
      STB(cur ^ 1, kt + 1, 3);                          // old buf B3: dead since kt-1.sub3
      asm volatile("s_waitcnt vmcnt(8)" ::: "memory");  // tile kt fully landed; t+1's 8 fly
    } else {
      asm volatile("s_waitcnt vmcnt(0)" ::: "memory");  // last tile: drain once
    }
    __builtin_amdgcn_s_barrier();
    __builtin_amdgcn_sched_barrier(0);
    short8 af[2][2], bfv[2][2];
    #pragma unroll
    for (int mi = 0; mi < 2; ++mi) {
      const int ra = wr + mi * 16 + lr;
      #pragma unroll
      for (int ks = 0; ks < 2; ++ks)
        af[mi][ks] = *(const short8*)(la + ra * 64 + (((ks * 4 + lk) ^ (ra & 7)) << 3));
    }
    #pragma unroll
    for (int ni = 0; ni < 2; ++ni) {
      const int rb = ni * 16 + lr;
      #pragma unroll
      for (int ks = 0; ks < 2; ++ks)
        bfv[ni][ks] = *(const short8*)(lb + rb * 64 + (((ks * 4 + lk) ^ (rb & 7)) << 3));
    }
    asm volatile("s_waitcnt lgkmcnt(0)" ::: "memory");
    __builtin_amdgcn_sched_barrier(0);
    __builtin_amdgcn_s_setprio(1);
    #pragma unroll
    for (int mi = 0; mi < 2; ++mi)
      #pragma unroll
      for (int ni = 0; ni < 2; ++ni)
        #pragma unroll
        for (int ks = 0; ks < 2; ++ks)
          acc[mi][ni] = __builtin_amdgcn_mfma_f32_16x16x32_bf16(af[mi][ks], bfv[ni][ks], acc[mi][ni], 0, 0, 0);
    __builtin_amdgcn_s_setprio(0);
    __builtin_amdgcn_s_barrier();                       // A + B0 of cur now dead

    // ---------- sub1..sub3: B-slab n2 reads; refill dead cur regions with t+2 ----------
    #pragma unroll
    for (int n2 = 1; n2 < 4; ++n2) {
      if (kt + 2 < nt) {
        if (n2 == 1) { STA(cur, kt + 2, 0); STA(cur, kt + 2, 1);
                       STA(cur, kt + 2, 2); STA(cur, kt + 2, 3);
                       STB(cur, kt + 2, 0); }
        else if (n2 == 2) { STB(cur, kt + 2, 1); }
        else              { STB(cur, kt + 2, 2); }
      }
      #pragma unroll
      for (int ni = 0; ni < 2; ++ni) {
        const int rb = (n2 * 2 + ni) * 16 + lr;
        #pragma unroll
        for (int ks = 0; ks < 2; ++ks)
          bfv[ni][ks] = *(const short8*)(lb + rb * 64 + (((ks * 4 + lk) ^ (rb & 7)) << 3));
      }
      asm volatile("s_waitcnt lgkmcnt(0)" ::: "memory");
      __builtin_amdgcn_sched_barrier(0);
      __builtin_amdgcn_s_setprio(1);
      #pragma unroll
      for (int mi = 0; mi < 2; ++mi)
        #pragma unroll
        for (int ni = 0; ni < 2; ++ni)
          #pragma unroll
          for (int ks = 0; ks < 2; ++ks)
            acc[mi][n2 * 2 + ni] = __builtin_amdgcn_mfma_f32_16x16x32_bf16(af[mi][ks], bfv[ni][ks], acc[mi][n2 * 2 + ni], 0, 0, 0);
      __builtin_amdgcn_s_setprio(0);
      __builtin_amdgcn_s_barrier();                     // B-slab n2 of cur now dead
    }
  }
  #undef STA
  #undef STB

  // ---- fused epilogue (in-register RoPE; no LDS, no barriers) ----
  const int bb2 = m0 >> 11;

  if (bn < 20) {
    const bool isq = (bn < 16);
    u16* obase = isq ? (qrout + (size_t)(bb2 * NH + bn) * SEQL * HD)
                     : (krout + (size_t)(bb2 * NKVH + (bn - 16)) * SEQL * HD);
    #pragma unroll
    for (int mi = 0; mi < 2; ++mi) {
      const int rbase = m0 + wr + mi * 16 + lk * 4;
      #pragma unroll
      for (int ni = 0; ni < 4; ++ni) {
        const int d64 = ni * 16 + lr;
        #pragma unroll
        for (int r = 0; r < 4; ++r) {
          const int s = (rbase + r) & (SEQL - 1);
          float x = acc[mi][ni][r];
          float y = acc[mi][ni + 4][r];
          float cc = cosT[(s << 6) + d64], ss = sinT[(s << 6) + d64];
          float o0 = x * cc - y * ss;
          float o1 = y * cc + x * ss;
          if (isq) { o0 *= C1F; o1 *= C1F; }
          obase[(size_t)s * HD + d64]      = f2bf(o0);
          obase[(size_t)s * HD + d64 + 64] = f2bf(o1);
        }
      }
    }
  } else {
    const int kvh = bn - 20;
    u16* vb = vtout + (size_t)(bb2 * NKVH + kvh) * HD * SEQL;
    #pragma unroll
    for (int mi = 0; mi < 2; ++mi) {
      const int s0 = (m0 + wr + mi * 16 + lk * 4) & (SEQL - 1);
      #pragma unroll
      for (int ni = 0; ni < 8; ++ni) {
        const int d = ni * 16 + lr;
        ushort4 w4;
        w4.x = f2bf(acc[mi][ni][0]); w4.y = f2bf(acc[mi][ni][1]);
        w4.z = f2bf(acc[mi][ni][2]); w4.w = f2bf(acc[mi][ni][3]);
        *(ushort4*)(vb + (size_t)d * SEQL + s0) = w4;
      }
    }
  }
}

// ---------------- AO GEMM: 128x64 tile, 1024 blocks (unchanged from R11) ----------
__global__ __launch_bounds__(256, 4) void k_gemm_ao(const u16* __restrict__ A,
                                                    const u16* __restrict__ Bm,
                                                    float* __restrict__ C,
                                                    int N, int K) {
  __shared__ __align__(16) u16 ldsA[128 * 64];   // 16 KB
  __shared__ __align__(16) u16 ldsB[64 * 64];    //  8 KB
  const int t = threadIdx.x;

  const int nwg  = gridDim.x * gridDim.y;
  const int flat = blockIdx.y * gridDim.x + blockIdx.x;
  const int cpx  = nwg >> 3;
  const int swz  = (flat & 7) * cpx + (flat >> 3);
  const int bn = swz % gridDim.x, bm = swz / gridDim.x;

  const int m0 = bm * 128, n0 = bn * 64;
  const int lane = t & 63, wid = t >> 6;
  const int lr = lane & 15, lk = lane >> 4;
  const int wr = (wid >> 1) * 64, wc = (wid & 1) * 32;
  const int nt = K >> 6;

  const int srow = t >> 3;
  const int scol = (((t & 7) ^ (srow & 7)) << 3);

  f32x4 acc[4][2];
  #pragma unroll
  for (int mi = 0; mi < 4; ++mi)
    #pragma unroll
    for (int ni = 0; ni < 2; ++ni) acc[mi][ni] = f32x4{0.f, 0.f, 0.f, 0.f};

  for (int kt = 0; kt < nt; ++kt) {
    {
      const u16* a0 = A  + (size_t)(m0 + srow) * K + kt * 64 + scol;
      const u16* b0 = Bm + (size_t)(n0 + srow) * K + kt * 64 + scol;
      #pragma unroll
      for (int i = 0; i < 4; ++i)
        gld16(a0 + (size_t)(i * 32) * K, &ldsA[i * 2048 + t * 8]);
      #pragma unroll
      for (int i = 0; i < 2; ++i)
        gld16(b0 + (size_t)(i * 32) * K, &ldsB[i * 2048 + t * 8]);
    }
    __syncthreads();
    #pragma unroll
    for (int ks = 0; ks < 2; ++ks) {
      const int c = ks * 4 + lk;
      short8 af[4], bfv[2];
      #pragma unroll
      for (int mi = 0; mi < 4; ++mi) {
        const int ra = wr + mi * 16 + lr;
        af[mi] = *(const short8*)(ldsA + ra * 64 + ((c ^ (ra & 7)) << 3));
      }
      #pragma unroll
      for (int ni = 0; ni < 2; ++ni) {
        const int rb = wc + ni * 16 + lr;
        bfv[ni] = *(const short8*)(ldsB + rb * 64 + ((c ^ (rb & 7)) << 3));
      }
      #pragma unroll
      for (int mi = 0; mi < 4; ++mi)
        #pragma unroll
        for (int ni = 0; ni < 2; ++ni)
          acc[mi][ni] = __builtin_amdgcn_mfma_f32_16x16x32_bf16(af[mi], bfv[ni], acc[mi][ni], 0, 0, 0);
    }
    if (kt + 1 < nt) __syncthreads();
  }

  #pragma unroll
  for (int mi = 0; mi < 4; ++mi) {
    #pragma unroll
    for (int ni = 0; ni < 2; ++ni) {
      const int r0 = m0 + wr + mi * 16 + lk * 4;
      const int c  = n0 + wc + ni * 16 + lr;
      #pragma unroll
      for (int r = 0; r < 4; ++r)
        C[(size_t)(r0 + r) * N + c] = acc[mi][ni][r];
    }
  }
}

// ---------------- flash attention (unchanged: 32x32x16, in-reg P) ----------
__global__ __launch_bounds__(256, 2) void k_attn(const u16* __restrict__ qr,
                                                 const u16* __restrict__ kr,
                                                 const u16* __restrict__ vt,
                                                 u16* __restrict__ ao) {
  __shared__ __align__(16) u16 kbuf[2][32 * 128];
  __shared__ __align__(16) u16 vbuf[2][128 * 32];

  const int t = threadIdx.x;
  const int wid = t >> 6, lane = t & 63;
  const int l31 = lane & 31, lh = lane >> 5;
  const int h = blockIdx.x, bq = blockIdx.y, b = blockIdx.z;
  const int kvh = h >> 2;
  const int Q0 = bq * 128;
  const int q0w = Q0 + wid * 32;
  const u16* qb = qr + (size_t)(b * NH + h) * SEQL * HD;
  const u16* kb = kr + (size_t)(b * NKVH + kvh) * SEQL * HD;
  const u16* vb = vt + (size_t)(b * NKVH + kvh) * HD * SEQL;

  short8 qf[8];
  #pragma unroll
  for (int ks = 0; ks < 8; ++ks)
    qf[ks] = *(const short8*)(qb + (size_t)(q0w + l31) * HD + ks * 16 + lh * 8);

  f32x16 o[4];
  #pragma unroll
  for (int dt = 0; dt < 4; ++dt)
    #pragma unroll
    for (int i = 0; i < 16; ++i) o[dt][i] = 0.f;
  float lsum = 0.f;

  int lo = Q0 - (WIN - 1); if (lo < 0) lo = 0;
  const int ktlo = lo >> 5, kthi = (Q0 + 127) >> 5;

  auto stageK = [&](int bufi, int kv0) {
    #pragma unroll
    for (int i = 0; i < 2; ++i) {
      int c = t + i * 256;
      int bb = c << 4;
      int sb = bb ^ (((bb >> 8) & 7) << 4);
      gld16(kb + (size_t)(kv0 + (sb >> 8)) * HD + ((sb & 255) >> 1),
            &kbuf[bufi][c << 3]);
    }
  };
  auto stageV = [&](int bufi, int kv0) {
    #pragma unroll
    for (int i = 0; i < 2; ++i) {
      int c = t + i * 256;
      int bb = c << 4;
      int sb = bb ^ (((bb >> 7) & 3) << 4);
      gld16(vb + (size_t)(sb >> 6) * SEQL + kv0 + ((sb & 63) >> 1),
            &vbuf[bufi][c << 3]);
    }
  };

  stageK(0, ktlo << 5);
  stageV(0, ktlo << 5);
  __syncthreads();

  for (int kt = ktlo; kt <= kthi; ++kt) {
    const int cur = kt & 1;
    if (kt < kthi) { stageK(cur ^ 1, (kt + 1) << 5); stageV(cur ^ 1, (kt + 1) << 5); }
    const int kv0 = kt << 5;
    if (kv0 + 31 >= q0w - (WIN - 1) && kv0 <= q0w + 31) {
      f32x16 sv;
      #pragma unroll
      for (int i = 0; i < 16; ++i) sv[i] = 0.f;
      const u16* lks = kbuf[cur];
      #pragma unroll
      for (int ks = 0; ks < 8; ++ks) {
        int bo = (l31 * 256 + ks * 32 + lh * 16) ^ ((l31 & 7) << 4);
        short8 kf = *(const short8*)(lks + (bo >> 1));
        sv = __builtin_amdgcn_mfma_f32_32x32x16_bf16(kf, qf[ks], sv, 0, 0, 0);
      }
      float p[16];
      const bool interior = (kv0 + 31 <= q0w) && (kv0 >= q0w + 32 - WIN);
      if (interior) {
        #pragma unroll
        for (int r = 0; r < 16; ++r) p[r] = exp_softcap(sv[r]);
      } else {
        const int qg = q0w + l31;
        #pragma unroll
        for (int r = 0; r < 16; ++r) {
          const int kg = kv0 + (r & 3) + 8 * (r >> 2) + 4 * lh;
          float e = exp_softcap(sv[r]);
          p[r] = (kg <= qg && kg > qg - WIN) ? e : 0.f;
        }
      }
      #pragma unroll
      for (int r = 0; r < 16; ++r) lsum += p[r];

      uint32_t w[8];
      #pragma unroll
      for (int r2 = 0; r2 < 8; ++r2) {
        __hip_bfloat162 u = __float22bfloat162_rn(float2{p[2 * r2], p[2 * r2 + 1]});
        w[r2] = *(uint32_t*)&u;
      }
      uint32_t z0 = lh ? w[0] : w[2], z1 = lh ? w[1] : w[3];
      uint32_t z2 = lh ? w[4] : w[6], z3 = lh ? w[5] : w[7];
      uint32_t x0 = __shfl_xor((int)z0, 32), x1 = __shfl_xor((int)z1, 32);
      uint32_t x2 = __shfl_xor((int)z2, 32), x3 = __shfl_xor((int)z3, 32);
      union U8 { uint32_t u[4]; short8 s; };
      U8 pa0, pa1;
      pa0.u[0] = lh ? x0 : w[0];  pa0.u[1] = lh ? x1 : w[1];
      pa0.u[2] = lh ? w[2] : x0;  pa0.u[3] = lh ? w[3] : x1;
      pa1.u[0] = lh ? x2 : w[4];  pa1.u[1] = lh ? x3 : w[5];
      pa1.u[2] = lh ? w[6] : x2;  pa1.u[3] = lh ? w[7] : x3;

      const u16* lvs = vbuf[cur];
      #pragma unroll
      for (int ks2 = 0; ks2 < 2; ++ks2) {
        const short8 paf = ks2 ? pa1.s : pa0.s;
        #pragma unroll
        for (int dt = 0; dt < 4; ++dt) {
          int row = dt * 32 + l31;
          int bo = (row * 64 + ks2 * 32 + lh * 16) ^ (((row >> 1) & 3) << 4);
          short8 vf = *(const short8*)(lvs + (bo >> 1));
          o[dt] = __builtin_amdgcn_mfma_f32_32x32x16_bf16(paf, vf, o[dt], 0, 0, 0);
        }
      }
    }
    __syncthreads();
  }

  lsum += __shfl_xor(lsum, 32);
  float linv = 1.0f / lsum;
  #pragma unroll
  for (int rr = 0; rr < 4; ++rr) {
    #pragma unroll
    for (int r = 0; r < 4; ++r) {
      const int crow = r + 8 * rr + 4 * lh;
      float inv = __shfl(linv, crow);
      const int srow = q0w + crow;
      u16* op = ao + (size_t)(b * SEQL + srow) * DM + h * HD;
      #pragma unroll
      for (int dt = 0; dt < 4; ++dt)
        op[dt * 32 + l31] = f2bf(o[dt][rr * 4 + r] * inv);
    }
  }
}

extern "C" void kernel_launch(void* const* d_in, const int* in_sizes, int n_in,
                              void* d_out, int out_size, void* d_ws, size_t ws_size,
                              hipStream_t stream) {
  (void)in_sizes; (void)n_in; (void)out_size; (void)ws_size;
  const float* hs = (const float*)d_in[0];
  const float* wq = (const float*)d_in[1];
  const float* wk = (const float*)d_in[2];
  const float* wv = (const float*)d_in[3];
  const float* wo = (const float*)d_in[4];
  float* out = (float*)d_out;

  u16* ws    = (u16*)d_ws;
  u16* A_bf  = ws;                      //  8,388,608  hs bf16 [4096][2048]
  u16* Wqkv  = A_bf + 8388608;          //  6,291,456  packed [3072][2048]
  u16* Wo    = Wqkv + 6291456;          //  4,194,304  [2048][2048]
  u16* q_r   = Wo + 4194304;            //  8,388,608  [b][h][s][128]
  u16* k_r   = q_r + 8388608;           //  2,097,152  [b][kvh][s][128]
  u16* vTb   = k_r + 2097152;           //  2,097,152  [b][kvh][128][s]
  float* cosT = (float*)(vTb + 2097152);
  float* sinT = cosT + 131072;
  u16* aout = A_bf;                     // reuse A_bf after QKV gemm

  k_prep<<<18944, 256, 0, stream>>>(hs, wq, wk, wv, wo, A_bf, Wqkv, Wo, cosT, sinT);

  k_gemm_qkv<<<dim3(NQKV / 128, MR / 128), 256, 0, stream>>>(A_bf, Wqkv, q_r, k_r, vTb,
                                                             cosT, sinT);

  k_attn<<<dim3(NH, SEQL / 128, BAT), 256, 0, stream>>>(q_r, k_r, vTb, aout);

  k_gemm_ao<<<dim3(DM / 64, MR / 128), 256, 0, stream>>>(aout, Wo, out, DM, DM);
}

// Round 13
// 164.351 us; speedup vs baseline: 1.4251x; 1.4251x over previous
//
#include <hip/hip_runtime.h>
#include <hip/hip_bf16.h>
#include <stdint.h>

// Problem constants
#define DM    2048
#define NH    16
#define NKVH  4
#define HD    128
#define WIN   512
#define SEQL  2048
#define BAT   2
#define MR    (BAT*SEQL)        // 4096 rows
#define NQKV  3072              // 2048 q + 512 k + 512 v
#define QKSCALE 0.08838834764831845f
#define CAP   50.0f
// C1: folded into Q in the fused GEMM epilogue. sv = y * 2*log2e/CAP, y = q.k*QKSCALE
#define C1F (QKSCALE * 2.0f * 1.4426950408889634f / CAP)
#define C2F (-144.26950408889634f)   // -2*CAP*log2e ; p' = 2^(C2F/(2^sv+1))

typedef unsigned short u16;
typedef __attribute__((ext_vector_type(8))) short short8;
typedef __attribute__((ext_vector_type(4))) float f32x4;
typedef __attribute__((ext_vector_type(16))) float f32x16;

__device__ __forceinline__ u16 f2bf(float f) {
  union { float f; uint32_t u; } v; v.f = f;
  uint32_t r = v.u + 0x7FFFu + ((v.u >> 16) & 1u);
  return (u16)(r >> 16);
}
__device__ __forceinline__ float bf2f(u16 h) {
  union { uint32_t u; float f; } v; v.u = ((uint32_t)h) << 16; return v.f;
}
__device__ __forceinline__ void gld16(const void* g, void* l) {
  __builtin_amdgcn_global_load_lds((const __attribute__((address_space(1))) void*)g,
                                   (__attribute__((address_space(3))) void*)l,
                                   16, 0, 0);
}
// p' = exp(CAP*tanh(y/CAP)) / e^CAP = 2^( C2F / (2^sv + 1) ), sv pre-scaled via C1F.
// Real intrinsics (not inline asm) so TRANS hazard wait-states are inserted (R6 fix).
__device__ __forceinline__ float exp_softcap(float sv) {
  float t = __builtin_amdgcn_exp2f(sv);
  float u = __builtin_amdgcn_rcpf(t + 1.0f);
  return __builtin_amdgcn_exp2f(u * C2F);
}

// ---------------- fused prep: all fp32->bf16 casts + RoPE table, one launch ----------
__global__ void k_prep(const float* __restrict__ hs, const float* __restrict__ wq,
                       const float* __restrict__ wk, const float* __restrict__ wv,
                       const float* __restrict__ wo,
                       u16* __restrict__ A_bf, u16* __restrict__ Wqkv,
                       u16* __restrict__ Wo,
                       float* __restrict__ cosT, float* __restrict__ sinT) {
  const int bid = blockIdx.x;
  if (bid < 18432) {
    const int g = bid * 256 + threadIdx.x;     // float4 index
    const float* src; u16* dst; int off;
    if (g < 2097152)      { src = hs; dst = A_bf;           off = 0; }
    else if (g < 3145728) { src = wq; dst = Wqkv;           off = 2097152; }
    else if (g < 3407872) { src = wk; dst = Wqkv + 4194304; off = 3145728; }
    else if (g < 3670016) { src = wv; dst = Wqkv + 5242880; off = 3407872; }
    else                  { src = wo; dst = Wo;             off = 3670016; }
    const int li = g - off;
    float4 v = ((const float4*)src)[li];
    ushort4 o;
    o.x = f2bf(v.x); o.y = f2bf(v.y); o.z = f2bf(v.z); o.w = f2bf(v.w);
    ((ushort4*)dst)[li] = o;
  } else {
    const int rt = (bid - 18432) * 256 + threadIdx.x;  // 0..131071
    const int s = rt >> 6, i = rt & 63;
    float invf = expf(-(float)i * (9.210340371976184f / 64.0f));
    float a = (float)s * invf;
    cosT[rt] = cosf(a);
    sinT[rt] = sinf(a);
  }
}

// ---------------- fused QKV GEMM: C = A * Wqkv^T with IN-REGISTER RoPE epilogue ----
// Wave layout 4M x 1N (wr = wid*32, full 128-col span per wave): the RoPE pair
// (d, d+64) is acc[mi][ni] / acc[mi][ni+4] in the SAME thread -> epilogue needs
// no LDS exchange and no barriers. Hot loop = m97 structure: single-buffered
// 32KB LDS, drain per tile, 3 blocks/CU (R12 lesson: counted-vmcnt grafts onto
// this structure REGRESS 2.3x - m131/m141 class; do not re-add).
__global__ __launch_bounds__(256, 3) void k_gemm_qkv(const u16* __restrict__ A,
                                                     const u16* __restrict__ Bm,
                                                     u16* __restrict__ qrout,
                                                     u16* __restrict__ krout,
                                                     u16* __restrict__ vtout,
                                                     const float* __restrict__ cosT,
                                                     const float* __restrict__ sinT) {
  __shared__ __align__(16) u16 ldsA[128 * 64];
  __shared__ __align__(16) u16 ldsB[128 * 64];
  const int t = threadIdx.x;
  const int K = DM;

  const int nwg  = gridDim.x * gridDim.y;               // 24*32 = 768, %8==0
  const int flat = blockIdx.y * gridDim.x + blockIdx.x;
  const int cpx  = nwg >> 3;
  const int swz  = (flat & 7) * cpx + (flat >> 3);
  const int bn = swz % gridDim.x, bm = swz / gridDim.x;

  const int m0 = bm * 128;
  const int lane = t & 63, wid = t >> 6;
  const int lr = lane & 15, lk = lane >> 4;
  const int wr = wid * 32;                              // 4M x 1N
  const int nt = K >> 6;

  const int srow = t >> 3;
  const int scol = (((t & 7) ^ (srow & 7)) << 3);       // T2 source swizzle

  f32x4 acc[2][8];
  #pragma unroll
  for (int mi = 0; mi < 2; ++mi)
    #pragma unroll
    for (int ni = 0; ni < 8; ++ni) acc[mi][ni] = f32x4{0.f, 0.f, 0.f, 0.f};

  for (int kt = 0; kt < nt; ++kt) {
    {
      const u16* a0 = A  + (size_t)(m0 + srow) * K + kt * 64 + scol;
      const u16* b0 = Bm + (size_t)(bn * 128 + srow) * K + kt * 64 + scol;
      #pragma unroll
      for (int i = 0; i < 4; ++i) {
        gld16(a0 + (size_t)(i * 32) * K, &ldsA[i * 2048 + t * 8]);
        gld16(b0 + (size_t)(i * 32) * K, &ldsB[i * 2048 + t * 8]);
      }
    }
    __syncthreads();
    #pragma unroll
    for (int ks = 0; ks < 2; ++ks) {
      const int c = ks * 4 + lk;
      short8 af[2], bfv[8];
      #pragma unroll
      for (int mi = 0; mi < 2; ++mi) {
        const int ra = wr + mi * 16 + lr;
        af[mi] = *(const short8*)(ldsA + ra * 64 + ((c ^ (ra & 7)) << 3));
      }
      #pragma unroll
      for (int ni = 0; ni < 8; ++ni) {
        const int rb = ni * 16 + lr;
        bfv[ni] = *(const short8*)(ldsB + rb * 64 + ((c ^ (rb & 7)) << 3));
      }
      #pragma unroll
      for (int mi = 0; mi < 2; ++mi)
        #pragma unroll
        for (int ni = 0; ni < 8; ++ni)
          acc[mi][ni] = __builtin_amdgcn_mfma_f32_16x16x32_bf16(af[mi], bfv[ni], acc[mi][ni], 0, 0, 0);
    }
    if (kt + 1 < nt) __syncthreads();
  }

  // ---- fused epilogue (no barriers, no LDS) ----
  const int bb2 = m0 >> 11;

  if (bn < 20) {
    const bool isq = (bn < 16);
    u16* obase = isq ? (qrout + (size_t)(bb2 * NH + bn) * SEQL * HD)
                     : (krout + (size_t)(bb2 * NKVH + (bn - 16)) * SEQL * HD);
    #pragma unroll
    for (int mi = 0; mi < 2; ++mi) {
      const int rbase = m0 + wr + mi * 16 + lk * 4;
      #pragma unroll
      for (int ni = 0; ni < 4; ++ni) {
        const int d64 = ni * 16 + lr;
        #pragma unroll
        for (int r = 0; r < 4; ++r) {
          const int s = (rbase + r) & (SEQL - 1);
          float x = acc[mi][ni][r];          // d = d64
          float y = acc[mi][ni + 4][r];      // d = d64 + 64
          float cc = cosT[(s << 6) + d64], ss = sinT[(s << 6) + d64];
          float o0 = x * cc - y * ss;
          float o1 = y * cc + x * ss;
          if (isq) { o0 *= C1F; o1 *= C1F; }
          obase[(size_t)s * HD + d64]      = f2bf(o0);
          obase[(size_t)s * HD + d64 + 64] = f2bf(o1);
        }
      }
    }
  } else {
    const int kvh = bn - 20;
    u16* vb = vtout + (size_t)(bb2 * NKVH + kvh) * HD * SEQL;
    #pragma unroll
    for (int mi = 0; mi < 2; ++mi) {
      const int s0 = (m0 + wr + mi * 16 + lk * 4) & (SEQL - 1);
      #pragma unroll
      for (int ni = 0; ni < 8; ++ni) {
        const int d = ni * 16 + lr;
        ushort4 w4;
        w4.x = f2bf(acc[mi][ni][0]); w4.y = f2bf(acc[mi][ni][1]);
        w4.z = f2bf(acc[mi][ni][2]); w4.w = f2bf(acc[mi][ni][3]);
        *(ushort4*)(vb + (size_t)d * SEQL + s0) = w4;
      }
    }
  }
}

// ---------------- AO GEMM: 128x64 tile -> 1024 blocks = 4 barrier domains/CU ----
__global__ __launch_bounds__(256, 4) void k_gemm_ao(const u16* __restrict__ A,
                                                    const u16* __restrict__ Bm,
                                                    float* __restrict__ C,
                                                    int N, int K) {
  __shared__ __align__(16) u16 ldsA[128 * 64];   // 16 KB
  __shared__ __align__(16) u16 ldsB[64 * 64];    //  8 KB
  const int t = threadIdx.x;

  const int nwg  = gridDim.x * gridDim.y;        // 32*32 = 1024, %8==0
  const int flat = blockIdx.y * gridDim.x + blockIdx.x;
  const int cpx  = nwg >> 3;
  const int swz  = (flat & 7) * cpx + (flat >> 3);
  const int bn = swz % gridDim.x, bm = swz / gridDim.x;

  const int m0 = bm * 128, n0 = bn * 64;
  const int lane = t & 63, wid = t >> 6;
  const int lr = lane & 15, lk = lane >> 4;
  const int wr = (wid >> 1) * 64, wc = (wid & 1) * 32;  // 2M x 2N, 64x32/wave
  const int nt = K >> 6;

  const int srow = t >> 3;
  const int scol = (((t & 7) ^ (srow & 7)) << 3);

  f32x4 acc[4][2];
  #pragma unroll
  for (int mi = 0; mi < 4; ++mi)
    #pragma unroll
    for (int ni = 0; ni < 2; ++ni) acc[mi][ni] = f32x4{0.f, 0.f, 0.f, 0.f};

  for (int kt = 0; kt < nt; ++kt) {
    {
      const u16* a0 = A  + (size_t)(m0 + srow) * K + kt * 64 + scol;
      const u16* b0 = Bm + (size_t)(n0 + srow) * K + kt * 64 + scol;
      #pragma unroll
      for (int i = 0; i < 4; ++i)
        gld16(a0 + (size_t)(i * 32) * K, &ldsA[i * 2048 + t * 8]);
      #pragma unroll
      for (int i = 0; i < 2; ++i)
        gld16(b0 + (size_t)(i * 32) * K, &ldsB[i * 2048 + t * 8]);
    }
    __syncthreads();
    #pragma unroll
    for (int ks = 0; ks < 2; ++ks) {
      const int c = ks * 4 + lk;
      short8 af[4], bfv[2];
      #pragma unroll
      for (int mi = 0; mi < 4; ++mi) {
        const int ra = wr + mi * 16 + lr;
        af[mi] = *(const short8*)(ldsA + ra * 64 + ((c ^ (ra & 7)) << 3));
      }
      #pragma unroll
      for (int ni = 0; ni < 2; ++ni) {
        const int rb = wc + ni * 16 + lr;
        bfv[ni] = *(const short8*)(ldsB + rb * 64 + ((c ^ (rb & 7)) << 3));
      }
      #pragma unroll
      for (int mi = 0; mi < 4; ++mi)
        #pragma unroll
        for (int ni = 0; ni < 2; ++ni)
          acc[mi][ni] = __builtin_amdgcn_mfma_f32_16x16x32_bf16(af[mi], bfv[ni], acc[mi][ni], 0, 0, 0);
    }
    if (kt + 1 < nt) __syncthreads();
  }

  #pragma unroll
  for (int mi = 0; mi < 4; ++mi) {
    #pragma unroll
    for (int ni = 0; ni < 2; ++ni) {
      const int r0 = m0 + wr + mi * 16 + lk * 4;
      const int c  = n0 + wc + ni * 16 + lr;
      #pragma unroll
      for (int r = 0; r < 4; ++r)
        C[(size_t)(r0 + r) * N + c] = acc[mi][ni][r];
    }
  }
}

// ---------------- flash attention (32x32x16, in-reg P) ----------
__global__ __launch_bounds__(256, 2) void k_attn(const u16* __restrict__ qr,
                                                 const u16* __restrict__ kr,
                                                 const u16* __restrict__ vt,
                                                 u16* __restrict__ ao) {
  __shared__ __align__(16) u16 kbuf[2][32 * 128];   // [kv][d], byte bits[6:4]^=row&7
  __shared__ __align__(16) u16 vbuf[2][128 * 32];   // [d][kv], byte bits[5:4]^=(row>>1)&3

  const int t = threadIdx.x;
  const int wid = t >> 6, lane = t & 63;
  const int l31 = lane & 31, lh = lane >> 5;
  const int h = blockIdx.x, bq = blockIdx.y, b = blockIdx.z;
  const int kvh = h >> 2;
  const int Q0 = bq * 128;
  const int q0w = Q0 + wid * 32;
  const u16* qb = qr + (size_t)(b * NH + h) * SEQL * HD;
  const u16* kb = kr + (size_t)(b * NKVH + kvh) * SEQL * HD;
  const u16* vb = vt + (size_t)(b * NKVH + kvh) * HD * SEQL;

  short8 qf[8];
  #pragma unroll
  for (int ks = 0; ks < 8; ++ks)
    qf[ks] = *(const short8*)(qb + (size_t)(q0w + l31) * HD + ks * 16 + lh * 8);

  f32x16 o[4];
  #pragma unroll
  for (int dt = 0; dt < 4; ++dt)
    #pragma unroll
    for (int i = 0; i < 16; ++i) o[dt][i] = 0.f;
  float lsum = 0.f;

  int lo = Q0 - (WIN - 1); if (lo < 0) lo = 0;
  const int ktlo = lo >> 5, kthi = (Q0 + 127) >> 5;

  auto stageK = [&](int bufi, int kv0) {
    #pragma unroll
    for (int i = 0; i < 2; ++i) {
      int c = t + i * 256;
      int bb = c << 4;
      int sb = bb ^ (((bb >> 8) & 7) << 4);
      gld16(kb + (size_t)(kv0 + (sb >> 8)) * HD + ((sb & 255) >> 1),
            &kbuf[bufi][c << 3]);
    }
  };
  auto stageV = [&](int bufi, int kv0) {
    #pragma unroll
    for (int i = 0; i < 2; ++i) {
      int c = t + i * 256;
      int bb = c << 4;
      int sb = bb ^ (((bb >> 7) & 3) << 4);
      gld16(vb + (size_t)(sb >> 6) * SEQL + kv0 + ((sb & 63) >> 1),
            &vbuf[bufi][c << 3]);
    }
  };

  stageK(0, ktlo << 5);
  stageV(0, ktlo << 5);
  __syncthreads();

  for (int kt = ktlo; kt <= kthi; ++kt) {
    const int cur = kt & 1;
    if (kt < kthi) { stageK(cur ^ 1, (kt + 1) << 5); stageV(cur ^ 1, (kt + 1) << 5); }
    const int kv0 = kt << 5;
    if (kv0 + 31 >= q0w - (WIN - 1) && kv0 <= q0w + 31) {
      f32x16 sv;
      #pragma unroll
      for (int i = 0; i < 16; ++i) sv[i] = 0.f;
      const u16* lks = kbuf[cur];
      #pragma unroll
      for (int ks = 0; ks < 8; ++ks) {
        int bo = (l31 * 256 + ks * 32 + lh * 16) ^ ((l31 & 7) << 4);
        short8 kf = *(const short8*)(lks + (bo >> 1));
        sv = __builtin_amdgcn_mfma_f32_32x32x16_bf16(kf, qf[ks], sv, 0, 0, 0);
      }
      float p[16];
      const bool interior = (kv0 + 31 <= q0w) && (kv0 >= q0w + 32 - WIN);
      if (interior) {
        #pragma unroll
        for (int r = 0; r < 16; ++r) p[r] = exp_softcap(sv[r]);
      } else {
        const int qg = q0w + l31;
        #pragma unroll
        for (int r = 0; r < 16; ++r) {
          const int kg = kv0 + (r & 3) + 8 * (r >> 2) + 4 * lh;
          float e = exp_softcap(sv[r]);
          p[r] = (kg <= qg && kg > qg - WIN) ? e : 0.f;
        }
      }
      #pragma unroll
      for (int r = 0; r < 16; ++r) lsum += p[r];

      uint32_t w[8];
      #pragma unroll
      for (int r2 = 0; r2 < 8; ++r2) {
        __hip_bfloat162 u = __float22bfloat162_rn(float2{p[2 * r2], p[2 * r2 + 1]});
        w[r2] = *(uint32_t*)&u;
      }
      uint32_t z0 = lh ? w[0] : w[2], z1 = lh ? w[1] : w[3];
      uint32_t z2 = lh ? w[4] : w[6], z3 = lh ? w[5] : w[7];
      uint32_t x0 = __shfl_xor((int)z0, 32), x1 = __shfl_xor((int)z1, 32);
      uint32_t x2 = __shfl_xor((int)z2, 32), x3 = __shfl_xor((int)z3, 32);
      union U8 { uint32_t u[4]; short8 s; };
      U8 pa0, pa1;
      pa0.u[0] = lh ? x0 : w[0];  pa0.u[1] = lh ? x1 : w[1];
      pa0.u[2] = lh ? w[2] : x0;  pa0.u[3] = lh ? w[3] : x1;
      pa1.u[0] = lh ? x2 : w[4];  pa1.u[1] = lh ? x3 : w[5];
      pa1.u[2] = lh ? w[6] : x2;  pa1.u[3] = lh ? w[7] : x3;

      const u16* lvs = vbuf[cur];
      #pragma unroll
      for (int ks2 = 0; ks2 < 2; ++ks2) {
        const short8 paf = ks2 ? pa1.s : pa0.s;
        #pragma unroll
        for (int dt = 0; dt < 4; ++dt) {
          int row = dt * 32 + l31;
          int bo = (row * 64 + ks2 * 32 + lh * 16) ^ (((row >> 1) & 3) << 4);
          short8 vf = *(const short8*)(lvs + (bo >> 1));
          o[dt] = __builtin_amdgcn_mfma_f32_32x32x16_bf16(paf, vf, o[dt], 0, 0, 0);
        }
      }
    }
    __syncthreads();
  }

  lsum += __shfl_xor(lsum, 32);
  float linv = 1.0f / lsum;
  #pragma unroll
  for (int rr = 0; rr < 4; ++rr) {
    #pragma unroll
    for (int r = 0; r < 4; ++r) {
      const int crow = r + 8 * rr + 4 * lh;
      float inv = __shfl(linv, crow);
      const int srow = q0w + crow;
      u16* op = ao + (size_t)(b * SEQL + srow) * DM + h * HD;
      #pragma unroll
      for (int dt = 0; dt < 4; ++dt)
        op[dt * 32 + l31] = f2bf(o[dt][rr * 4 + r] * inv);
    }
  }
}

extern "C" void kernel_launch(void* const* d_in, const int* in_sizes, int n_in,
                              void* d_out, int out_size, void* d_ws, size_t ws_size,
                              hipStream_t stream) {
  (void)in_sizes; (void)n_in; (void)out_size; (void)ws_size;
  const float* hs = (const float*)d_in[0];
  const float* wq = (const float*)d_in[1];
  const float* wk = (const float*)d_in[2];
  const float* wv = (const float*)d_in[3];
  const float* wo = (const float*)d_in[4];
  float* out = (float*)d_out;

  u16* ws    = (u16*)d_ws;
  u16* A_bf  = ws;                      //  8,388,608  hs bf16 [4096][2048]
  u16* Wqkv  = A_bf + 8388608;          //  6,291,456  packed [3072][2048]
  u16* Wo    = Wqkv + 6291456;          //  4,194,304  [2048][2048]
  u16* q_r   = Wo + 4194304;            //  8,388,608  [b][h][s][128]
  u16* k_r   = q_r + 8388608;           //  2,097,152  [b][kvh][s][128]
  u16* vTb   = k_r + 2097152;           //  2,097,152  [b][kvh][128][s]
  float* cosT = (float*)(vTb + 2097152);
  float* sinT = cosT + 131072;
  u16* aout = A_bf;                     // reuse A_bf after QKV gemm

  // one fused prep launch: 5 casts + rope table
  k_prep<<<18944, 256, 0, stream>>>(hs, wq, wk, wv, wo, A_bf, Wqkv, Wo, cosT, sinT);

  // fused QKV GEMM + in-register RoPE + V-transpose
  k_gemm_qkv<<<dim3(NQKV / 128, MR / 128), 256, 0, stream>>>(A_bf, Wqkv, q_r, k_r, vTb,
                                                             cosT, sinT);

  k_attn<<<dim3(NH, SEQL / 128, BAT), 256, 0, stream>>>(q_r, k_r, vTb, aout);

  // AO projection: 128x64 tiles -> 1024 blocks = 4 barrier domains/CU
  k_gemm_ao<<<dim3(DM / 64, MR / 128), 256, 0, stream>>>(aout, Wo, out, DM, DM);
}

// Round 14
// 160.378 us; speedup vs baseline: 1.4604x; 1.0248x over previous
//
#include <hip/hip_runtime.h>
#include <hip/hip_bf16.h>
#include <stdint.h>

// Problem constants
#define DM    2048
#define NH    16
#define NKVH  4
#define HD    128
#define WIN   512
#define SEQL  2048
#define BAT   2
#define MR    (BAT*SEQL)        // 4096 rows
#define NQKV  3072              // 2048 q + 512 k + 512 v
#define QKSCALE 0.08838834764831845f
#define CAP   50.0f
// C1: folded into Q in the fused GEMM epilogue. sv = y * 2*log2e/CAP, y = q.k*QKSCALE
#define C1F (QKSCALE * 2.0f * 1.4426950408889634f / CAP)
#define C2F (-144.26950408889634f)   // -2*CAP*log2e ; p' = 2^(C2F/(2^sv+1))

typedef unsigned short u16;
typedef __attribute__((ext_vector_type(8))) short short8;
typedef __attribute__((ext_vector_type(4))) float f32x4;
typedef __attribute__((ext_vector_type(16))) float f32x16;

__device__ __forceinline__ u16 f2bf(float f) {
  union { float f; uint32_t u; } v; v.f = f;
  uint32_t r = v.u + 0x7FFFu + ((v.u >> 16) & 1u);
  return (u16)(r >> 16);
}
__device__ __forceinline__ float bf2f(u16 h) {
  union { uint32_t u; float f; } v; v.u = ((uint32_t)h) << 16; return v.f;
}
__device__ __forceinline__ void gld16(const void* g, void* l) {
  __builtin_amdgcn_global_load_lds((const __attribute__((address_space(1))) void*)g,
                                   (__attribute__((address_space(3))) void*)l,
                                   16, 0, 0);
}
// p' = exp(CAP*tanh(y/CAP)) / e^CAP = 2^( C2F / (2^sv + 1) ), sv pre-scaled via C1F.
// Real intrinsics (not inline asm) so TRANS hazard wait-states are inserted (R6 fix).
__device__ __forceinline__ float exp_softcap(float sv) {
  float t = __builtin_amdgcn_exp2f(sv);
  float u = __builtin_amdgcn_rcpf(t + 1.0f);
  return __builtin_amdgcn_exp2f(u * C2F);
}

// ---------------- fused prep: all fp32->bf16 casts + RoPE table, one launch ----------
__global__ void k_prep(const float* __restrict__ hs, const float* __restrict__ wq,
                       const float* __restrict__ wk, const float* __restrict__ wv,
                       const float* __restrict__ wo,
                       u16* __restrict__ A_bf, u16* __restrict__ Wqkv,
                       u16* __restrict__ Wo,
                       float* __restrict__ cosT, float* __restrict__ sinT) {
  const int bid = blockIdx.x;
  if (bid < 18432) {
    const int g = bid * 256 + threadIdx.x;     // float4 index
    const float* src; u16* dst; int off;
    if (g < 2097152)      { src = hs; dst = A_bf;           off = 0; }
    else if (g < 3145728) { src = wq; dst = Wqkv;           off = 2097152; }
    else if (g < 3407872) { src = wk; dst = Wqkv + 4194304; off = 3145728; }
    else if (g < 3670016) { src = wv; dst = Wqkv + 5242880; off = 3407872; }
    else                  { src = wo; dst = Wo;             off = 3670016; }
    const int li = g - off;
    float4 v = ((const float4*)src)[li];
    ushort4 o;
    o.x = f2bf(v.x); o.y = f2bf(v.y); o.z = f2bf(v.z); o.w = f2bf(v.w);
    ((ushort4*)dst)[li] = o;
  } else {
    const int rt = (bid - 18432) * 256 + threadIdx.x;  // 0..131071
    const int s = rt >> 6, i = rt & 63;
    float invf = expf(-(float)i * (9.210340371976184f / 64.0f));
    float a = (float)s * invf;
    cosT[rt] = cosf(a);
    sinT[rt] = sinf(a);
  }
}

// ---------------- fused QKV GEMM: C = A * Wqkv^T with IN-REGISTER RoPE epilogue ----
// Wave layout 4M x 1N (wr = wid*32, full 128-col span per wave): the RoPE pair
// (d, d+64) is acc[mi][ni] / acc[mi][ni+4] in the SAME thread -> epilogue needs
// no LDS exchange and no barriers. Hot loop = m97 structure: single-buffered
// 32KB LDS, drain per tile, 3 blocks/CU (R12 lesson: counted-vmcnt grafts onto
// this structure REGRESS 2.3x - m131/m141 class; do not re-add).
__global__ __launch_bounds__(256, 3) void k_gemm_qkv(const u16* __restrict__ A,
                                                     const u16* __restrict__ Bm,
                                                     u16* __restrict__ qrout,
                                                     u16* __restrict__ krout,
                                                     u16* __restrict__ vtout,
                                                     const float* __restrict__ cosT,
                                                     const float* __restrict__ sinT) {
  __shared__ __align__(16) u16 ldsA[128 * 64];
  __shared__ __align__(16) u16 ldsB[128 * 64];
  const int t = threadIdx.x;
  const int K = DM;

  const int nwg  = gridDim.x * gridDim.y;               // 24*32 = 768, %8==0
  const int flat = blockIdx.y * gridDim.x + blockIdx.x;
  const int cpx  = nwg >> 3;
  const int swz  = (flat & 7) * cpx + (flat >> 3);
  const int bn = swz % gridDim.x, bm = swz / gridDim.x;

  const int m0 = bm * 128;
  const int lane = t & 63, wid = t >> 6;
  const int lr = lane & 15, lk = lane >> 4;
  const int wr = wid * 32;                              // 4M x 1N
  const int nt = K >> 6;

  const int srow = t >> 3;
  const int scol = (((t & 7) ^ (srow & 7)) << 3);       // T2 source swizzle

  f32x4 acc[2][8];
  #pragma unroll
  for (int mi = 0; mi < 2; ++mi)
    #pragma unroll
    for (int ni = 0; ni < 8; ++ni) acc[mi][ni] = f32x4{0.f, 0.f, 0.f, 0.f};

  for (int kt = 0; kt < nt; ++kt) {
    {
      const u16* a0 = A  + (size_t)(m0 + srow) * K + kt * 64 + scol;
      const u16* b0 = Bm + (size_t)(bn * 128 + srow) * K + kt * 64 + scol;
      #pragma unroll
      for (int i = 0; i < 4; ++i) {
        gld16(a0 + (size_t)(i * 32) * K, &ldsA[i * 2048 + t * 8]);
        gld16(b0 + (size_t)(i * 32) * K, &ldsB[i * 2048 + t * 8]);
      }
    }
    __syncthreads();
    #pragma unroll
    for (int ks = 0; ks < 2; ++ks) {
      const int c = ks * 4 + lk;
      short8 af[2], bfv[8];
      #pragma unroll
      for (int mi = 0; mi < 2; ++mi) {
        const int ra = wr + mi * 16 + lr;
        af[mi] = *(const short8*)(ldsA + ra * 64 + ((c ^ (ra & 7)) << 3));
      }
      #pragma unroll
      for (int ni = 0; ni < 8; ++ni) {
        const int rb = ni * 16 + lr;
        bfv[ni] = *(const short8*)(ldsB + rb * 64 + ((c ^ (rb & 7)) << 3));
      }
      #pragma unroll
      for (int mi = 0; mi < 2; ++mi)
        #pragma unroll
        for (int ni = 0; ni < 8; ++ni)
          acc[mi][ni] = __builtin_amdgcn_mfma_f32_16x16x32_bf16(af[mi], bfv[ni], acc[mi][ni], 0, 0, 0);
    }
    if (kt + 1 < nt) __syncthreads();
  }

  // ---- fused epilogue (no barriers, no LDS) ----
  const int bb2 = m0 >> 11;

  if (bn < 20) {
    const bool isq = (bn < 16);
    u16* obase = isq ? (qrout + (size_t)(bb2 * NH + bn) * SEQL * HD)
                     : (krout + (size_t)(bb2 * NKVH + (bn - 16)) * SEQL * HD);
    #pragma unroll
    for (int mi = 0; mi < 2; ++mi) {
      const int rbase = m0 + wr + mi * 16 + lk * 4;
      #pragma unroll
      for (int ni = 0; ni < 4; ++ni) {
        const int d64 = ni * 16 + lr;
        #pragma unroll
        for (int r = 0; r < 4; ++r) {
          const int s = (rbase + r) & (SEQL - 1);
          float x = acc[mi][ni][r];          // d = d64
          float y = acc[mi][ni + 4][r];      // d = d64 + 64
          float cc = cosT[(s << 6) + d64], ss = sinT[(s << 6) + d64];
          float o0 = x * cc - y * ss;
          float o1 = y * cc + x * ss;
          if (isq) { o0 *= C1F; o1 *= C1F; }
          obase[(size_t)s * HD + d64]      = f2bf(o0);
          obase[(size_t)s * HD + d64 + 64] = f2bf(o1);
        }
      }
    }
  } else {
    const int kvh = bn - 20;
    u16* vb = vtout + (size_t)(bb2 * NKVH + kvh) * HD * SEQL;
    #pragma unroll
    for (int mi = 0; mi < 2; ++mi) {
      const int s0 = (m0 + wr + mi * 16 + lk * 4) & (SEQL - 1);
      #pragma unroll
      for (int ni = 0; ni < 8; ++ni) {
        const int d = ni * 16 + lr;
        ushort4 w4;
        w4.x = f2bf(acc[mi][ni][0]); w4.y = f2bf(acc[mi][ni][1]);
        w4.z = f2bf(acc[mi][ni][2]); w4.w = f2bf(acc[mi][ni][3]);
        *(ushort4*)(vb + (size_t)d * SEQL + s0) = w4;
      }
    }
  }
}

// ---------------- AO GEMM: 128x64 tile -> 1024 blocks = 4 barrier domains/CU ----
__global__ __launch_bounds__(256, 4) void k_gemm_ao(const u16* __restrict__ A,
                                                    const u16* __restrict__ Bm,
                                                    float* __restrict__ C,
                                                    int N, int K) {
  __shared__ __align__(16) u16 ldsA[128 * 64];   // 16 KB
  __shared__ __align__(16) u16 ldsB[64 * 64];    //  8 KB
  const int t = threadIdx.x;

  const int nwg  = gridDim.x * gridDim.y;        // 32*32 = 1024, %8==0
  const int flat = blockIdx.y * gridDim.x + blockIdx.x;
  const int cpx  = nwg >> 3;
  const int swz  = (flat & 7) * cpx + (flat >> 3);
  const int bn = swz % gridDim.x, bm = swz / gridDim.x;

  const int m0 = bm * 128, n0 = bn * 64;
  const int lane = t & 63, wid = t >> 6;
  const int lr = lane & 15, lk = lane >> 4;
  const int wr = (wid >> 1) * 64, wc = (wid & 1) * 32;  // 2M x 2N, 64x32/wave
  const int nt = K >> 6;

  const int srow = t >> 3;
  const int scol = (((t & 7) ^ (srow & 7)) << 3);

  f32x4 acc[4][2];
  #pragma unroll
  for (int mi = 0; mi < 4; ++mi)
    #pragma unroll
    for (int ni = 0; ni < 2; ++ni) acc[mi][ni] = f32x4{0.f, 0.f, 0.f, 0.f};

  for (int kt = 0; kt < nt; ++kt) {
    {
      const u16* a0 = A  + (size_t)(m0 + srow) * K + kt * 64 + scol;
      const u16* b0 = Bm + (size_t)(n0 + srow) * K + kt * 64 + scol;
      #pragma unroll
      for (int i = 0; i < 4; ++i)
        gld16(a0 + (size_t)(i * 32) * K, &ldsA[i * 2048 + t * 8]);
      #pragma unroll
      for (int i = 0; i < 2; ++i)
        gld16(b0 + (size_t)(i * 32) * K, &ldsB[i * 2048 + t * 8]);
    }
    __syncthreads();
    #pragma unroll
    for (int ks = 0; ks < 2; ++ks) {
      const int c = ks * 4 + lk;
      short8 af[4], bfv[2];
      #pragma unroll
      for (int mi = 0; mi < 4; ++mi) {
        const int ra = wr + mi * 16 + lr;
        af[mi] = *(const short8*)(ldsA + ra * 64 + ((c ^ (ra & 7)) << 3));
      }
      #pragma unroll
      for (int ni = 0; ni < 2; ++ni) {
        const int rb = wc + ni * 16 + lr;
        bfv[ni] = *(const short8*)(ldsB + rb * 64 + ((c ^ (rb & 7)) << 3));
      }
      #pragma unroll
      for (int mi = 0; mi < 4; ++mi)
        #pragma unroll
        for (int ni = 0; ni < 2; ++ni)
          acc[mi][ni] = __builtin_amdgcn_mfma_f32_16x16x32_bf16(af[mi], bfv[ni], acc[mi][ni], 0, 0, 0);
    }
    if (kt + 1 < nt) __syncthreads();
  }

  #pragma unroll
  for (int mi = 0; mi < 4; ++mi) {
    #pragma unroll
    for (int ni = 0; ni < 2; ++ni) {
      const int r0 = m0 + wr + mi * 16 + lk * 4;
      const int c  = n0 + wc + ni * 16 + lr;
      #pragma unroll
      for (int r = 0; r < 4; ++r)
        C[(size_t)(r0 + r) * N + c] = acc[mi][ni][r];
    }
  }
}

// ---------------- flash attention: 64-kv double-buffered tiles, 32x32x16 MFMA ----
// R13->R14: tile grain 32->64 kv. Halves barrier count (~20->~10 iters/block),
// doubles intra-phase ILP (16 indep MFMAs per QK/PV phase, 32 indep exps).
// LDS 64KB (2 blocks/CU; grid 512 = exactly 2/CU). Same swizzle class re-derived:
// K [64][128] chunk bits[6:4]^=row&7; V [128][64] chunk bits[6:4]^=row&7.
__global__ __launch_bounds__(256, 2) void k_attn(const u16* __restrict__ qr,
                                                 const u16* __restrict__ kr,
                                                 const u16* __restrict__ vt,
                                                 u16* __restrict__ ao) {
  __shared__ __align__(16) u16 kbuf[2][64 * 128];   // 16 KB each
  __shared__ __align__(16) u16 vbuf[2][128 * 64];   // 16 KB each

  const int t = threadIdx.x;
  const int wid = t >> 6, lane = t & 63;
  const int l31 = lane & 31, lh = lane >> 5;
  const int h = blockIdx.x, bq = blockIdx.y, b = blockIdx.z;
  const int kvh = h >> 2;
  const int Q0 = bq * 128;
  const int q0w = Q0 + wid * 32;
  const u16* qb = qr + (size_t)(b * NH + h) * SEQL * HD;
  const u16* kb = kr + (size_t)(b * NKVH + kvh) * SEQL * HD;
  const u16* vb = vt + (size_t)(b * NKVH + kvh) * HD * SEQL;

  // Q as B-frag for 32x32x16: lane holds Q[q0w+l31][ks*16 + lh*8 + j]
  short8 qf[8];
  #pragma unroll
  for (int ks = 0; ks < 8; ++ks)
    qf[ks] = *(const short8*)(qb + (size_t)(q0w + l31) * HD + ks * 16 + lh * 8);

  f32x16 o[4];
  #pragma unroll
  for (int dt = 0; dt < 4; ++dt)
    #pragma unroll
    for (int i = 0; i < 16; ++i) o[dt][i] = 0.f;
  float lsum = 0.f;                       // partial for q = q0w + l31

  int lo = Q0 - (WIN - 1); if (lo < 0) lo = 0;
  const int t_lo = lo >> 6, t_hi = (Q0 + 127) >> 6;

  // stage K tile [64 kv][128 d] (16 KB): byte bits[6:4] ^= row&7 (row = byte>>8)
  auto stageK = [&](int bufi, int kv0) {
    #pragma unroll
    for (int i = 0; i < 4; ++i) {
      int C = t + i * 256;                // 16B chunk 0..1023
      int bb = C << 4;
      int sb = bb ^ (((bb >> 8) & 7) << 4);
      gld16(kb + (size_t)(kv0 + (sb >> 8)) * HD + ((sb & 255) >> 1),
            &kbuf[bufi][C << 3]);
    }
  };
  // stage V^T tile [128 d][64 kv] (16 KB): byte bits[6:4] ^= row&7 (row = byte>>7)
  auto stageV = [&](int bufi, int kv0) {
    #pragma unroll
    for (int i = 0; i < 4; ++i) {
      int C = t + i * 256;
      int bb = C << 4;
      int sb = bb ^ (((bb >> 7) & 7) << 4);
      gld16(vb + (size_t)(sb >> 7) * SEQL + kv0 + ((sb & 127) >> 1),
            &vbuf[bufi][C << 3]);
    }
  };

  stageK(0, t_lo << 6);
  stageV(0, t_lo << 6);
  __syncthreads();

  for (int kt = t_lo; kt <= t_hi; ++kt) {
    const int cur = kt & 1;
    if (kt < t_hi) { stageK(cur ^ 1, (kt + 1) << 6); stageV(cur ^ 1, (kt + 1) << 6); }
    const int kv0 = kt << 6;
    // wave-uniform skip: q rows q0w..q0w+31 vs kv kv0..kv0+63
    if (kv0 + 63 >= q0w - (WIN - 1) && kv0 <= q0w + 31) {
      // QK^T swapped: A = K rows (two 32-kv groups), B = Q -> S^T[kv][q]
      f32x16 sv[2];
      #pragma unroll
      for (int g = 0; g < 2; ++g)
        #pragma unroll
        for (int i = 0; i < 16; ++i) sv[g][i] = 0.f;
      const u16* lks = kbuf[cur];
      #pragma unroll
      for (int g = 0; g < 2; ++g) {
        #pragma unroll
        for (int ks = 0; ks < 8; ++ks) {
          const int row = g * 32 + l31;     // row&7 == l31&7
          int bo = (row * 256 + ks * 32 + lh * 16) ^ ((l31 & 7) << 4);
          short8 kf = *(const short8*)(lks + (bo >> 1));
          sv[g] = __builtin_amdgcn_mfma_f32_32x32x16_bf16(kf, qf[ks], sv[g], 0, 0, 0);
        }
      }
      // p' = exp(softcap)/e^CAP per score; mask only on boundary tiles
      float p[2][16];
      const bool interior = (kv0 + 63 <= q0w) && (kv0 >= q0w + 32 - WIN);
      if (interior) {
        #pragma unroll
        for (int g = 0; g < 2; ++g)
          #pragma unroll
          for (int r = 0; r < 16; ++r) p[g][r] = exp_softcap(sv[g][r]);
      } else {
        const int qg = q0w + l31;
        #pragma unroll
        for (int g = 0; g < 2; ++g)
          #pragma unroll
          for (int r = 0; r < 16; ++r) {
            const int kg = kv0 + g * 32 + (r & 3) + 8 * (r >> 2) + 4 * lh;
            float e = exp_softcap(sv[g][r]);
            p[g][r] = (kg <= qg && kg > qg - WIN) ? e : 0.f;
          }
      }
      #pragma unroll
      for (int g = 0; g < 2; ++g)
        #pragma unroll
        for (int r = 0; r < 16; ++r) lsum += p[g][r];

      // pack p -> bf16 A-frags in-register (cvt_pk pairs + cross-half shfl)
      union U8 { uint32_t u[4]; short8 s; };
      U8 pa[2][2];
      #pragma unroll
      for (int g = 0; g < 2; ++g) {
        uint32_t w[8];
        #pragma unroll
        for (int r2 = 0; r2 < 8; ++r2) {
          __hip_bfloat162 u = __float22bfloat162_rn(float2{p[g][2 * r2], p[g][2 * r2 + 1]});
          w[r2] = *(uint32_t*)&u;
        }
        uint32_t z0 = lh ? w[0] : w[2], z1 = lh ? w[1] : w[3];
        uint32_t z2 = lh ? w[4] : w[6], z3 = lh ? w[5] : w[7];
        uint32_t x0 = __shfl_xor((int)z0, 32), x1 = __shfl_xor((int)z1, 32);
        uint32_t x2 = __shfl_xor((int)z2, 32), x3 = __shfl_xor((int)z3, 32);
        pa[g][0].u[0] = lh ? x0 : w[0];  pa[g][0].u[1] = lh ? x1 : w[1];
        pa[g][0].u[2] = lh ? w[2] : x0;  pa[g][0].u[3] = lh ? w[3] : x1;
        pa[g][1].u[0] = lh ? x2 : w[4];  pa[g][1].u[1] = lh ? x3 : w[5];
        pa[g][1].u[2] = lh ? w[6] : x2;  pa[g][1].u[3] = lh ? w[7] : x3;
      }

      // PV: A = P (32q x 16kv frags), B = V^T rows -> O[q][d], 4 d-tiles of 32
      const u16* lvs = vbuf[cur];
      #pragma unroll
      for (int g = 0; g < 2; ++g) {
        #pragma unroll
        for (int ks2 = 0; ks2 < 2; ++ks2) {
          const short8 paf = pa[g][ks2].s;
          const int m16 = g * 2 + ks2;      // 16-kv group 0..3
          #pragma unroll
          for (int dt = 0; dt < 4; ++dt) {
            const int row = dt * 32 + l31;
            int bo = (row * 128 + (m16 * 2 + lh) * 16) ^ ((row & 7) << 4);
            short8 vf = *(const short8*)(lvs + (bo >> 1));
            o[dt] = __builtin_amdgcn_mfma_f32_32x32x16_bf16(paf, vf, o[dt], 0, 0, 0);
          }
        }
      }
    }
    __syncthreads();
  }

  // epilogue: lsum at q = q0w+l31 (merge lh halves); O rows crow-mapped
  lsum += __shfl_xor(lsum, 32);
  float linv = 1.0f / lsum;
  #pragma unroll
  for (int rr = 0; rr < 4; ++rr) {
    #pragma unroll
    for (int r = 0; r < 4; ++r) {
      const int crow = r + 8 * rr + 4 * lh;
      float inv = __shfl(linv, crow);
      const int srow = q0w + crow;
      u16* op = ao + (size_t)(b * SEQL + srow) * DM + h * HD;
      #pragma unroll
      for (int dt = 0; dt < 4; ++dt)
        op[dt * 32 + l31] = f2bf(o[dt][rr * 4 + r] * inv);
    }
  }
}

extern "C" void kernel_launch(void* const* d_in, const int* in_sizes, int n_in,
                              void* d_out, int out_size, void* d_ws, size_t ws_size,
                              hipStream_t stream) {
  (void)in_sizes; (void)n_in; (void)out_size; (void)ws_size;
  const float* hs = (const float*)d_in[0];
  const float* wq = (const float*)d_in[1];
  const float* wk = (const float*)d_in[2];
  const float* wv = (const float*)d_in[3];
  const float* wo = (const float*)d_in[4];
  float* out = (float*)d_out;

  u16* ws    = (u16*)d_ws;
  u16* A_bf  = ws;                      //  8,388,608  hs bf16 [4096][2048]
  u16* Wqkv  = A_bf + 8388608;          //  6,291,456  packed [3072][2048]
  u16* Wo    = Wqkv + 6291456;          //  4,194,304  [2048][2048]
  u16* q_r   = Wo + 4194304;            //  8,388,608  [b][h][s][128]
  u16* k_r   = q_r + 8388608;           //  2,097,152  [b][kvh][s][128]
  u16* vTb   = k_r + 2097152;           //  2,097,152  [b][kvh][128][s]
  float* cosT = (float*)(vTb + 2097152);
  float* sinT = cosT + 131072;
  u16* aout = A_bf;                     // reuse A_bf after QKV gemm

  // one fused prep launch: 5 casts + rope table
  k_prep<<<18944, 256, 0, stream>>>(hs, wq, wk, wv, wo, A_bf, Wqkv, Wo, cosT, sinT);

  // fused QKV GEMM + in-register RoPE + V-transpose
  k_gemm_qkv<<<dim3(NQKV / 128, MR / 128), 256, 0, stream>>>(A_bf, Wqkv, q_r, k_r, vTb,
                                                             cosT, sinT);

  k_attn<<<dim3(NH, SEQL / 128, BAT), 256, 0, stream>>>(q_r, k_r, vTb, aout);

  // AO projection: 128x64 tiles -> 1024 blocks = 4 barrier domains/CU
  k_gemm_ao<<<dim3(DM / 64, MR / 128), 256, 0, stream>>>(aout, Wo, out, DM, DM);
}